// Round 6
// baseline (360.562 us; speedup 1.0000x reference)
//
#include <hip/hip_runtime.h>
#include <cstdint>

using u16 = unsigned short;
using u32 = unsigned int;

constexpr int kB  = 4096;
constexpr int kE  = 512;
constexpr int kT  = 32;
constexpr int kH  = 256;
constexpr int kIT = 5;
constexpr float kEPS = 1e-6f;

typedef __attribute__((ext_vector_type(8)))  short short8;
typedef __attribute__((ext_vector_type(16))) float floatx16;
typedef __attribute__((ext_vector_type(8)))  u16   ushort8;
typedef __attribute__((ext_vector_type(4)))  float floatv4;  // native vec for nt builtins

__device__ __forceinline__ u16 f2bf(float f) {
  u32 u = __builtin_bit_cast(u32, f);
  return (u16)((u + 0x7fffu + ((u >> 16) & 1u)) >> 16);
}

__device__ __forceinline__ floatx16 mfma32(short8 a, short8 b, floatx16 c) {
  return __builtin_amdgcn_mfma_f32_32x32x16_bf16(a, b, c, 0, 0, 0);
}

__device__ __forceinline__ float4 ntload4(const float* p) {
  floatv4 v = __builtin_nontemporal_load((const floatv4*)p);
  return __builtin_bit_cast(float4, v);
}
__device__ __forceinline__ void ntstore4(float* p, float4 v) {
  __builtin_nontemporal_store(__builtin_bit_cast(floatv4, v), (floatv4*)p);
}

// ---------------- combined prepass v2: fully-coalesced, nt loads ----------------
// xp chunk c = slab*64 + ks*2 + mt : lane l holds row=slab*64+mt*32+(l&31), k=ks*16+(l>>5)*8+j
// wp chunk c = t*512 + ks*16 + ntile*2 + mat : lane l holds n=ntile*32+(l&31), k=ks*16+(l>>5)*8+j
__global__ __launch_bounds__(256) void pack_kernel(
    const float* __restrict__ x, const float* __restrict__ w_in,
    const float* __restrict__ w_val, u16* __restrict__ xp, u16* __restrict__ wp) {
  const int bid = blockIdx.x;
  if (bid < 1024) {
    // ---- x part: identical mapping to R4 (verified), nt float4 loads ----
    const int gt = bid * 256 + threadIdx.x;
    const int lane = gt & 63, c = gt >> 6;
    const int mt = c & 1, ks = (c >> 1) & 31, slab = c >> 6;
    const int row = slab * 64 + mt * 32 + (lane & 31);
    const int k   = ks * 16 + (lane >> 5) * 8;
    const float4 f0 = ntload4(x + (size_t)row * kE + k);
    const float4 f1 = ntload4(x + (size_t)row * kE + k + 4);
    ushort8 o;
    o[0] = f2bf(f0.x); o[1] = f2bf(f0.y); o[2] = f2bf(f0.z); o[3] = f2bf(f0.w);
    o[4] = f2bf(f1.x); o[5] = f2bf(f1.y); o[6] = f2bf(f1.z); o[7] = f2bf(f1.w);
    *(ushort8*)(xp + (size_t)c * 512 + lane * 8) = o;
  } else {
    // ---- w part: 64e x 64n LDS transpose tile per block ----
    __shared__ float tile[64 * 68];
    const int wb   = bid - 1024;
    const int tl   = wb & 31;          // tile within (t,mat)
    const int et   = tl >> 2;          // e-tile 0..7  (e0 = et*64)
    const int ht   = tl & 3;           // h-tile 0..3  (h0 = ht*64)
    const int tm   = wb >> 5;
    const int t    = tm >> 1, mat = tm & 1;
    const int tid  = threadIdx.x;
    const float* src = (mat ? w_val : w_in) + (size_t)t * kE * kH +
                       (size_t)(et * 64) * kH + ht * 64;
    // load: 64 rows x 64 cols fp32, float4-coalesced (nt)
    const int lrow = tid >> 4, lc4 = (tid & 15) * 4;
#pragma unroll
    for (int p = 0; p < 4; ++p) {
      const int e = lrow + p * 16;
      const float4 v = ntload4(src + (size_t)e * kH + lc4);
      tile[e * 68 + lc4 + 0] = v.x; tile[e * 68 + lc4 + 1] = v.y;
      tile[e * 68 + lc4 + 2] = v.z; tile[e * 68 + lc4 + 3] = v.w;
    }
    __syncthreads();
    // store: 8 chunks (4 ks_l x 2 nt_l); thread (ks_l = tid>>6, lane) does both nt_l
    const int ks_l = tid >> 6, lane = tid & 63;
    const int kloc = ks_l * 16 + (lane >> 5) * 8;
#pragma unroll
    for (int nt_l = 0; nt_l < 2; ++nt_l) {
      const int nloc = nt_l * 32 + (lane & 31);
      ushort8 o;
#pragma unroll
      for (int j = 0; j < 8; ++j) o[j] = f2bf(tile[(kloc + j) * 68 + nloc]);
      const int c = t * 512 + (et * 4 + ks_l) * 16 + (ht * 2 + nt_l) * 2 + mat;
      *(ushort8*)(wp + (size_t)c * 512 + lane * 8) = o;
    }
  }
}

// ---------------- fused: barrier-free K-loop, direct coalesced fragment loads ----
// block = 64 rows x 256 cols; 4 waves n-split; wave tile 64x64 (2mt x 2nt), dual GEMM.
__global__ __launch_bounds__(256) void fused_kernel(
    const u16* __restrict__ xp, const u16* __restrict__ wp,
    const float* __restrict__ alphas, const float* __restrict__ scales,
    const float* __restrict__ gamma, const float* __restrict__ beta,
    float* __restrict__ out) {
  __shared__ __attribute__((aligned(16))) float sAcc[32 * 256];  // 32KB

  const int tid  = threadIdx.x;
  const int wv   = tid >> 6;
  const int lane = tid & 63;
  const int l31  = lane & 31;
  const int h    = lane >> 5;

  const int bid  = blockIdx.x;
  const int xcd  = bid & 7, j_ = bid >> 3;
  const int t    = j_ >> 3;
  const int slab = ((j_ & 7) << 3) | xcd;

  const u16* xpb = xp + (size_t)slab * (32 * 2 * 512) + lane * 8;
  const u16* wpb = wp + (size_t)t * (32 * 16 * 512) + (size_t)(wv * 2) * 1024 + lane * 8;

  floatx16 ai[2][2], av[2][2];
#pragma unroll
  for (int m = 0; m < 2; ++m)
#pragma unroll
    for (int n = 0; n < 2; ++n) { ai[m][n] = (floatx16)0.f; av[m][n] = (floatx16)0.f; }

  short8 A[2][2], BI[2][2], BV[2][2];
  A[0][0]  = *(const short8*)(xpb);
  A[0][1]  = *(const short8*)(xpb + 512);
  BI[0][0] = *(const short8*)(wpb);
  BV[0][0] = *(const short8*)(wpb + 512);
  BI[0][1] = *(const short8*)(wpb + 1024);
  BV[0][1] = *(const short8*)(wpb + 1536);

#pragma unroll
  for (int ks = 0; ks < 32; ++ks) {
    const int cur = ks & 1, nx = cur ^ 1;
    const int kn = (ks < 31) ? ks + 1 : 31;
    A[nx][0]  = *(const short8*)(xpb + kn * 1024);
    A[nx][1]  = *(const short8*)(xpb + kn * 1024 + 512);
    BI[nx][0] = *(const short8*)(wpb + kn * 8192);
    BV[nx][0] = *(const short8*)(wpb + kn * 8192 + 512);
    BI[nx][1] = *(const short8*)(wpb + kn * 8192 + 1024);
    BV[nx][1] = *(const short8*)(wpb + kn * 8192 + 1536);
    ai[0][0] = mfma32(A[cur][0], BI[cur][0], ai[0][0]);
    ai[1][0] = mfma32(A[cur][1], BI[cur][0], ai[1][0]);
    ai[0][1] = mfma32(A[cur][0], BI[cur][1], ai[0][1]);
    ai[1][1] = mfma32(A[cur][1], BI[cur][1], ai[1][1]);
    av[0][0] = mfma32(A[cur][0], BV[cur][0], av[0][0]);
    av[1][0] = mfma32(A[cur][1], BV[cur][0], av[1][0]);
    av[0][1] = mfma32(A[cur][0], BV[cur][1], av[0][1]);
    av[1][1] = mfma32(A[cur][1], BV[cur][1], av[1][1]);
  }

  // ---- epilogue (verified in R4; nt final stores) ----
  const float inv_h = 1.0f / kH;
  float al[kIT];
#pragma unroll
  for (int i = 0; i < kIT; ++i) al[i] = alphas[t * kIT + i] * inv_h;

  const int row_r = tid >> 3;
  const int seg   = tid & 7;
  const int r4    = (row_r & 7) << 2;

  for (int mt = 0; mt < 2; ++mt) {
    __syncthreads();
#pragma unroll
    for (int nt = 0; nt < 2; ++nt)
#pragma unroll
      for (int q = 0; q < 16; ++q) {
        const int r   = (q & 3) + 8 * (q >> 2) + 4 * h;
        const int col = wv * 64 + nt * 32 + l31;
        sAcc[r * 256 + (col ^ ((r & 7) << 2))] = ai[mt][nt][q];
      }
    __syncthreads();

    float4 xt[8];
#pragma unroll
    for (int j = 0; j < 8; ++j) {
      xt[j] = *(const float4*)(sAcc + row_r * 256 + seg * 32 + ((4 * j) ^ r4));
#pragma unroll
      for (int i = 0; i < 4; ++i) xt[j][i] = fmaxf(xt[j][i], 0.f);
    }

#pragma unroll
    for (int it = 0; it < kIT; ++it) {
      float4 s4 = xt[0];
#pragma unroll
      for (int j = 1; j < 8; ++j) s4 += xt[j];
      float v = s4.x + s4.y + s4.z + s4.w;
      v += __shfl_xor(v, 1, 8);
      v += __shfl_xor(v, 2, 8);
      v += __shfl_xor(v, 4, 8);
      const float m = al[it] * v;
#pragma unroll
      for (int j = 0; j < 8; ++j)
#pragma unroll
        for (int i = 0; i < 4; ++i) xt[j][i] = fmaxf(xt[j][i] - m, 0.f);
    }

    __syncthreads();
#pragma unroll
    for (int nt = 0; nt < 2; ++nt)
#pragma unroll
      for (int q = 0; q < 16; ++q) {
        const int r   = (q & 3) + 8 * (q >> 2) + 4 * h;
        const int col = wv * 64 + nt * 32 + l31;
        sAcc[r * 256 + (col ^ ((r & 7) << 2))] = av[mt][nt][q];
      }
    __syncthreads();

    float4 res[8];
    float sum = 0.f, ssq = 0.f;
#pragma unroll
    for (int j = 0; j < 8; ++j) {
      const int cb = seg * 32 + ((4 * j) ^ r4);  // physical LDS offset
      const int lc = seg * 32 + 4 * j;           // logical column
      const float4 a4 = *(const float4*)(sAcc + row_r * 256 + cb);
      const float4 sc = *(const float4*)(scales + t * kH + lc);
      float4 s;
#pragma unroll
      for (int i = 0; i < 4; ++i) {
        s[i] = sc[i] * xt[j][i] * a4[i];
        sum += s[i];
        ssq += s[i] * s[i];
      }
      res[j] = s;
    }
    sum += __shfl_xor(sum, 1, 8);  ssq += __shfl_xor(ssq, 1, 8);
    sum += __shfl_xor(sum, 2, 8);  ssq += __shfl_xor(ssq, 2, 8);
    sum += __shfl_xor(sum, 4, 8);  ssq += __shfl_xor(ssq, 4, 8);
    const float mu  = sum * inv_h;
    const float var = ssq * inv_h - mu * mu;
    const float rs  = rsqrtf(var + kEPS);

#pragma unroll
    for (int j = 0; j < 8; ++j) {
      const int cb = seg * 32 + ((4 * j) ^ r4);
      const int lc = seg * 32 + 4 * j;
      const float4 g4 = *(const float4*)(gamma + t * kH + lc);
      const float4 b4 = *(const float4*)(beta + t * kH + lc);
      float4 o;
#pragma unroll
      for (int i = 0; i < 4; ++i) o[i] = (res[j][i] - mu) * rs * g4[i] + b4[i];
      *(float4*)(sAcc + row_r * 256 + cb) = o;
    }
    __syncthreads();

    // coalesced non-temporal sweep: keep output stream out of L2
#pragma unroll
    for (int r8 = 0; r8 < 8; ++r8) {
      const int rr = wv * 8 + r8;
      const int rb = (rr & 7) << 2;
      const float4 v = *(const float4*)(sAcc + rr * 256 + ((4 * lane) ^ rb));
      ntstore4(out + (size_t)(slab * 64 + mt * 32 + rr) * (kT * kH) + t * kH + 4 * lane, v);
    }
  }
}

extern "C" void kernel_launch(void* const* d_in, const int* in_sizes, int n_in,
                              void* d_out, int out_size, void* d_ws, size_t ws_size,
                              hipStream_t stream) {
  const float* x      = (const float*)d_in[0];
  const float* w_in   = (const float*)d_in[1];
  const float* w_val  = (const float*)d_in[2];
  const float* alphas = (const float*)d_in[3];
  const float* scales = (const float*)d_in[4];
  const float* gamma  = (const float*)d_in[5];
  const float* beta   = (const float*)d_in[6];
  float* out = (float*)d_out;

  // ws: xp 4MB (64*32*2 chunks * 1KB) | wp 16MB (32*32*16 chunks * 1KB)
  u16* xp = (u16*)d_ws;
  u16* wp = xp + (size_t)64 * 32 * 2 * 512;

  pack_kernel<<<1024 + 2048, 256, 0, stream>>>(x, w_in, w_val, xp, wp);
  fused_kernel<<<kT * (kB / 64), 256, 0, stream>>>(xp, wp, alphas, scales,
                                                   gamma, beta, out);
}

// Round 7
// 349.469 us; speedup vs baseline: 1.0317x; 1.0317x over previous
//
#include <hip/hip_runtime.h>
#include <cstdint>

using u16 = unsigned short;
using u32 = unsigned int;

constexpr int kB  = 4096;
constexpr int kE  = 512;
constexpr int kT  = 32;
constexpr int kH  = 256;
constexpr int kIT = 5;
constexpr float kEPS = 1e-6f;

typedef __attribute__((ext_vector_type(8)))  short short8;
typedef __attribute__((ext_vector_type(16))) float floatx16;
typedef __attribute__((ext_vector_type(8)))  u16   ushort8;
typedef __attribute__((ext_vector_type(4)))  float floatv4;  // native vec for nt builtins

__device__ __forceinline__ u16 f2bf(float f) {
  u32 u = __builtin_bit_cast(u32, f);
  return (u16)((u + 0x7fffu + ((u >> 16) & 1u)) >> 16);
}

__device__ __forceinline__ floatx16 mfma32(short8 a, short8 b, floatx16 c) {
  return __builtin_amdgcn_mfma_f32_32x32x16_bf16(a, b, c, 0, 0, 0);
}

__device__ __forceinline__ float4 ntload4(const float* p) {
  floatv4 v = __builtin_nontemporal_load((const floatv4*)p);
  return __builtin_bit_cast(float4, v);
}
__device__ __forceinline__ void ntstore4(float* p, float4 v) {
  __builtin_nontemporal_store(__builtin_bit_cast(floatv4, v), (floatv4*)p);
}

// ---------------- combined prepass v2: fully-coalesced, nt loads ----------------
// xp chunk c = slab*64 + ks*2 + mt : lane l holds row=slab*64+mt*32+(l&31), k=ks*16+(l>>5)*8+j
// wp chunk c = t*512 + ks*16 + ntile*2 + mat : lane l holds n=ntile*32+(l&31), k=ks*16+(l>>5)*8+j
__global__ __launch_bounds__(256) void pack_kernel(
    const float* __restrict__ x, const float* __restrict__ w_in,
    const float* __restrict__ w_val, u16* __restrict__ xp, u16* __restrict__ wp) {
  const int bid = blockIdx.x;
  if (bid < 1024) {
    // ---- x part: identical mapping to R4 (verified), nt float4 loads ----
    const int gt = bid * 256 + threadIdx.x;
    const int lane = gt & 63, c = gt >> 6;
    const int mt = c & 1, ks = (c >> 1) & 31, slab = c >> 6;
    const int row = slab * 64 + mt * 32 + (lane & 31);
    const int k   = ks * 16 + (lane >> 5) * 8;
    const float4 f0 = ntload4(x + (size_t)row * kE + k);
    const float4 f1 = ntload4(x + (size_t)row * kE + k + 4);
    ushort8 o;
    o[0] = f2bf(f0.x); o[1] = f2bf(f0.y); o[2] = f2bf(f0.z); o[3] = f2bf(f0.w);
    o[4] = f2bf(f1.x); o[5] = f2bf(f1.y); o[6] = f2bf(f1.z); o[7] = f2bf(f1.w);
    *(ushort8*)(xp + (size_t)c * 512 + lane * 8) = o;
  } else {
    // ---- w part: 64e x 64n LDS transpose tile per block ----
    __shared__ float tile[64 * 68];
    const int wb   = bid - 1024;
    const int tl   = wb & 31;          // tile within (t,mat)
    const int et   = tl >> 2;          // e-tile 0..7  (e0 = et*64)
    const int ht   = tl & 3;           // h-tile 0..3  (h0 = ht*64)
    const int tm   = wb >> 5;
    const int t    = tm >> 1, mat = tm & 1;
    const int tid  = threadIdx.x;
    const float* src = (mat ? w_val : w_in) + (size_t)t * kE * kH +
                       (size_t)(et * 64) * kH + ht * 64;
    // load: 64 rows x 64 cols fp32, float4-coalesced (nt)
    const int lrow = tid >> 4, lc4 = (tid & 15) * 4;
#pragma unroll
    for (int p = 0; p < 4; ++p) {
      const int e = lrow + p * 16;
      const float4 v = ntload4(src + (size_t)e * kH + lc4);
      tile[e * 68 + lc4 + 0] = v.x; tile[e * 68 + lc4 + 1] = v.y;
      tile[e * 68 + lc4 + 2] = v.z; tile[e * 68 + lc4 + 3] = v.w;
    }
    __syncthreads();
    // store: 8 chunks (4 ks_l x 2 nt_l); thread (ks_l = tid>>6, lane) does both nt_l
    const int ks_l = tid >> 6, lane = tid & 63;
    const int kloc = ks_l * 16 + (lane >> 5) * 8;
#pragma unroll
    for (int nt_l = 0; nt_l < 2; ++nt_l) {
      const int nloc = nt_l * 32 + (lane & 31);
      ushort8 o;
#pragma unroll
      for (int j = 0; j < 8; ++j) o[j] = f2bf(tile[(kloc + j) * 68 + nloc]);
      const int c = t * 512 + (et * 4 + ks_l) * 16 + (ht * 2 + nt_l) * 2 + mat;
      *(ushort8*)(wp + (size_t)c * 512 + lane * 8) = o;
    }
  }
}

// ---------------- fused: barrier-free K-loop, direct coalesced fragment loads ----
// block = 64 rows x 256 cols; 4 waves n-split; wave tile 64x64 (2mt x 2nt), dual GEMM.
// Supertile scheduling: XCD x (= bid&7) owns tokens [4x,4x+4); its 256 blocks run as
// 4 supertiles of (16 slabs x 4 tokens) = 64 resident blocks -> per-XCD L2 set:
// 4 tokens * 512KB W + 16 slabs * 64KB x = 3MB < 4MB L2; W reused across supertiles.
__global__ __launch_bounds__(256) void fused_kernel(
    const u16* __restrict__ xp, const u16* __restrict__ wp,
    const float* __restrict__ alphas, const float* __restrict__ scales,
    const float* __restrict__ gamma, const float* __restrict__ beta,
    float* __restrict__ out) {
  __shared__ __attribute__((aligned(16))) float sAcc[32 * 256];  // 32KB

  const int tid  = threadIdx.x;
  const int wv   = tid >> 6;
  const int lane = tid & 63;
  const int l31  = lane & 31;
  const int h    = lane >> 5;

  const int bid  = blockIdx.x;
  const int xcd  = bid & 7;          // XCD heuristic (bid % 8)
  const int r_   = bid >> 3;         // 0..255 within XCD
  const int st   = r_ >> 6;          // supertile 0..3 (slab group)
  const int wi   = r_ & 63;          // within supertile
  const int t    = xcd * 4 + (wi >> 4);
  const int slab = st * 16 + (wi & 15);

  const u16* xpb = xp + (size_t)slab * (32 * 2 * 512) + lane * 8;
  const u16* wpb = wp + (size_t)t * (32 * 16 * 512) + (size_t)(wv * 2) * 1024 + lane * 8;

  floatx16 ai[2][2], av[2][2];
#pragma unroll
  for (int m = 0; m < 2; ++m)
#pragma unroll
    for (int n = 0; n < 2; ++n) { ai[m][n] = (floatx16)0.f; av[m][n] = (floatx16)0.f; }

  short8 A[2][2], BI[2][2], BV[2][2];
  A[0][0]  = *(const short8*)(xpb);
  A[0][1]  = *(const short8*)(xpb + 512);
  BI[0][0] = *(const short8*)(wpb);
  BV[0][0] = *(const short8*)(wpb + 512);
  BI[0][1] = *(const short8*)(wpb + 1024);
  BV[0][1] = *(const short8*)(wpb + 1536);

#pragma unroll
  for (int ks = 0; ks < 32; ++ks) {
    const int cur = ks & 1, nx = cur ^ 1;
    const int kn = (ks < 31) ? ks + 1 : 31;
    A[nx][0]  = *(const short8*)(xpb + kn * 1024);
    A[nx][1]  = *(const short8*)(xpb + kn * 1024 + 512);
    BI[nx][0] = *(const short8*)(wpb + kn * 8192);
    BV[nx][0] = *(const short8*)(wpb + kn * 8192 + 512);
    BI[nx][1] = *(const short8*)(wpb + kn * 8192 + 1024);
    BV[nx][1] = *(const short8*)(wpb + kn * 8192 + 1536);
    ai[0][0] = mfma32(A[cur][0], BI[cur][0], ai[0][0]);
    ai[1][0] = mfma32(A[cur][1], BI[cur][0], ai[1][0]);
    ai[0][1] = mfma32(A[cur][0], BI[cur][1], ai[0][1]);
    ai[1][1] = mfma32(A[cur][1], BI[cur][1], ai[1][1]);
    av[0][0] = mfma32(A[cur][0], BV[cur][0], av[0][0]);
    av[1][0] = mfma32(A[cur][1], BV[cur][0], av[1][0]);
    av[0][1] = mfma32(A[cur][0], BV[cur][1], av[0][1]);
    av[1][1] = mfma32(A[cur][1], BV[cur][1], av[1][1]);
  }

  // ---- epilogue (verified in R4; nt final stores) ----
  const float inv_h = 1.0f / kH;
  float al[kIT];
#pragma unroll
  for (int i = 0; i < kIT; ++i) al[i] = alphas[t * kIT + i] * inv_h;

  const int row_r = tid >> 3;
  const int seg   = tid & 7;
  const int r4    = (row_r & 7) << 2;

  for (int mt = 0; mt < 2; ++mt) {
    __syncthreads();
#pragma unroll
    for (int nt = 0; nt < 2; ++nt)
#pragma unroll
      for (int q = 0; q < 16; ++q) {
        const int r   = (q & 3) + 8 * (q >> 2) + 4 * h;
        const int col = wv * 64 + nt * 32 + l31;
        sAcc[r * 256 + (col ^ ((r & 7) << 2))] = ai[mt][nt][q];
      }
    __syncthreads();

    float4 xt[8];
#pragma unroll
    for (int j = 0; j < 8; ++j) {
      xt[j] = *(const float4*)(sAcc + row_r * 256 + seg * 32 + ((4 * j) ^ r4));
#pragma unroll
      for (int i = 0; i < 4; ++i) xt[j][i] = fmaxf(xt[j][i], 0.f);
    }

#pragma unroll
    for (int it = 0; it < kIT; ++it) {
      float4 s4 = xt[0];
#pragma unroll
      for (int j = 1; j < 8; ++j) s4 += xt[j];
      float v = s4.x + s4.y + s4.z + s4.w;
      v += __shfl_xor(v, 1, 8);
      v += __shfl_xor(v, 2, 8);
      v += __shfl_xor(v, 4, 8);
      const float m = al[it] * v;
#pragma unroll
      for (int j = 0; j < 8; ++j)
#pragma unroll
        for (int i = 0; i < 4; ++i) xt[j][i] = fmaxf(xt[j][i] - m, 0.f);
    }

    __syncthreads();
#pragma unroll
    for (int nt = 0; nt < 2; ++nt)
#pragma unroll
      for (int q = 0; q < 16; ++q) {
        const int r   = (q & 3) + 8 * (q >> 2) + 4 * h;
        const int col = wv * 64 + nt * 32 + l31;
        sAcc[r * 256 + (col ^ ((r & 7) << 2))] = av[mt][nt][q];
      }
    __syncthreads();

    float4 res[8];
    float sum = 0.f, ssq = 0.f;
#pragma unroll
    for (int j = 0; j < 8; ++j) {
      const int cb = seg * 32 + ((4 * j) ^ r4);  // physical LDS offset
      const int lc = seg * 32 + 4 * j;           // logical column
      const float4 a4 = *(const float4*)(sAcc + row_r * 256 + cb);
      const float4 sc = *(const float4*)(scales + t * kH + lc);
      float4 s;
#pragma unroll
      for (int i = 0; i < 4; ++i) {
        s[i] = sc[i] * xt[j][i] * a4[i];
        sum += s[i];
        ssq += s[i] * s[i];
      }
      res[j] = s;
    }
    sum += __shfl_xor(sum, 1, 8);  ssq += __shfl_xor(ssq, 1, 8);
    sum += __shfl_xor(sum, 2, 8);  ssq += __shfl_xor(ssq, 2, 8);
    sum += __shfl_xor(sum, 4, 8);  ssq += __shfl_xor(ssq, 4, 8);
    const float mu  = sum * inv_h;
    const float var = ssq * inv_h - mu * mu;
    const float rs  = rsqrtf(var + kEPS);

#pragma unroll
    for (int j = 0; j < 8; ++j) {
      const int cb = seg * 32 + ((4 * j) ^ r4);
      const int lc = seg * 32 + 4 * j;
      const float4 g4 = *(const float4*)(gamma + t * kH + lc);
      const float4 b4 = *(const float4*)(beta + t * kH + lc);
      float4 o;
#pragma unroll
      for (int i = 0; i < 4; ++i) o[i] = (res[j][i] - mu) * rs * g4[i] + b4[i];
      *(float4*)(sAcc + row_r * 256 + cb) = o;
    }
    __syncthreads();

    // coalesced non-temporal sweep: keep output stream out of L2
#pragma unroll
    for (int r8 = 0; r8 < 8; ++r8) {
      const int rr = wv * 8 + r8;
      const int rb = (rr & 7) << 2;
      const float4 v = *(const float4*)(sAcc + rr * 256 + ((4 * lane) ^ rb));
      ntstore4(out + (size_t)(slab * 64 + mt * 32 + rr) * (kT * kH) + t * kH + 4 * lane, v);
    }
  }
}

extern "C" void kernel_launch(void* const* d_in, const int* in_sizes, int n_in,
                              void* d_out, int out_size, void* d_ws, size_t ws_size,
                              hipStream_t stream) {
  const float* x      = (const float*)d_in[0];
  const float* w_in   = (const float*)d_in[1];
  const float* w_val  = (const float*)d_in[2];
  const float* alphas = (const float*)d_in[3];
  const float* scales = (const float*)d_in[4];
  const float* gamma  = (const float*)d_in[5];
  const float* beta   = (const float*)d_in[6];
  float* out = (float*)d_out;

  // ws: xp 4MB (64*32*2 chunks * 1KB) | wp 16MB (32*32*16 chunks * 1KB)
  u16* xp = (u16*)d_ws;
  u16* wp = xp + (size_t)64 * 32 * 2 * 512;

  pack_kernel<<<1024 + 2048, 256, 0, stream>>>(x, w_in, w_val, xp, wp);
  fused_kernel<<<kT * (kB / 64), 256, 0, stream>>>(xp, wp, alphas, scales,
                                                   gamma, beta, out);
}